// Round 13
// baseline (158.307 us; speedup 1.0000x reference)
//
#include <hip/hip_runtime.h>
#include <math.h>

#define B_   128
#define N_   50
#define FIN  64
#define D_   64
#define BN   6400        // B*N
#define EPSF 1e-5f
// F(1,254) upper 0.05 critical value: pval > 0.05  <=>  fstat < FCRIT
#define FCRIT 3.8783305f

__device__ __forceinline__ float wsum(float v){
#pragma unroll
  for(int o=32;o>0;o>>=1) v += __shfl_xor(v,o);
  return v;
}
__device__ __forceinline__ float wmax(float v){
#pragma unroll
  for(int o=32;o>0;o>>=1) v = fmaxf(v,__shfl_xor(v,o));
  return v;
}
__device__ __forceinline__ float leaky(float x){ return x >= 0.f ? x : 0.2f*x; }

// K2m: fused (x@W -> hT in LDS) + softmax state + 50 submodel preds via
// one-term deletion + residual-moment atomics. 2 blocks/batch, 25 p's each.
// Block bx==0 also publishes h, s_i, s_j to global for K4a.
__global__ __launch_bounds__(512) void k2m(
    const float* __restrict__ x, const float* __restrict__ labels,
    const float* __restrict__ emb, const float* __restrict__ W,
    const float* __restrict__ att_i, const float* __restrict__ att_j,
    const float* __restrict__ att_em_i, const float* __restrict__ att_em_j,
    const float* __restrict__ bn1_g, const float* __restrict__ bn1_b,
    const float* __restrict__ bn1_rm, const float* __restrict__ bn1_rv,
    const float* __restrict__ bn2_g, const float* __restrict__ bn2_b,
    const float* __restrict__ bn2_rm, const float* __restrict__ bn2_rv,
    const float* __restrict__ gat_bias, const float* __restrict__ out_w,
    const float* __restrict__ out_b,
    float* __restrict__ h, float* __restrict__ s_i, float* __restrict__ s_j,
    float2* __restrict__ acc){
  __shared__ float wl[64*64];      // W
  __shared__ float xl[50*65];      // x rows, padded
  __shared__ float hT[64*53];      // h transposed [d][q], stride-53
  __shared__ float sl_i[64], sl_j[64];
  __shared__ float el[8*64];
  __shared__ float2 wc[8*64];
  __shared__ float4 hcl[64];       // folded eval-BN/head constants
  __shared__ float  hil[64];       // i2g
  int tid = threadIdx.x, w = tid>>6, lane = tid&63;
  int b = blockIdx.y, p0 = blockIdx.x*25;

  // ---- stage W, x; fold constants (proven in R8 fused P1) ----
  { const float4* W4 = (const float4*)W;
    float4* wl4 = (float4*)wl;
    for(int i=tid;i<1024;i+=512) wl4[i] = W4[i]; }
  { const float* xb = x + (size_t)b*N_*64;
    for(int i=tid;i<3200;i+=512) xl[(i>>6)*65 + (i&63)] = xb[i]; }
  if(tid<64){
    float i1g = bn1_g[tid]/sqrtf(bn1_rv[tid]+EPSF);
    float i2g = bn2_g[tid]/sqrtf(bn2_rv[tid]+EPSF);
    float C1 = i1g*gat_bias[tid] + bn1_b[tid] - bn1_rm[tid]*i1g;
    float C2 = bn2_b[tid] - bn2_rm[tid]*i2g;
    hcl[tid] = make_float4(i1g, C1, C2, out_w[tid]);
    hil[tid] = i2g;
  }
  __syncthreads();

  // ---- hT[d][q] = (x @ W)[q][d] (proven in R8 fused P1b) ----
#pragma unroll
  for(int it=0; it<2; ++it){
    int idx4 = tid + it*512;
    if(idx4 < 800){
      int q = idx4 >> 4, d4 = idx4 & 15;
      const float4* wrow = (const float4*)wl;
      float4 a = make_float4(0.f,0.f,0.f,0.f);
#pragma unroll
      for(int k=0;k<64;k++){
        float xv = xl[q*65+k];
        float4 wv = wrow[k*16+d4];
        a.x=fmaf(xv,wv.x,a.x); a.y=fmaf(xv,wv.y,a.y);
        a.z=fmaf(xv,wv.z,a.z); a.w=fmaf(xv,wv.w,a.w);
      }
      int d0 = d4*4;
      hT[(d0  )*53+q]=a.x; hT[(d0+1)*53+q]=a.y;
      hT[(d0+2)*53+q]=a.z; hT[(d0+3)*53+q]=a.w;
      if(blockIdx.x==0){                   // publish h row-major for K4a
        float4* hg = (float4*)(h + (size_t)b*N_*64);
        hg[q*16+d4] = a;
      }
    }
  }
  __syncthreads();

  // ---- s_i, s_j (proven in R8 fused P1c); bx==0 publishes to global ----
  for(int q=w; q<N_; q+=8){
    float hv = hT[lane*53+q];
    float ev = emb[q*64+lane];
    float si = wsum(fmaf(hv, att_i[lane], ev*att_em_i[lane]));
    float sj = wsum(fmaf(hv, att_j[lane], ev*att_em_j[lane]));
    if(lane==0){
      sl_i[q]=si; sl_j[q]=sj;
      if(blockIdx.x==0){ s_i[b*N_+q]=si; s_j[b*N_+q]=sj; }
    }
  }
  __syncthreads();

  // ---- phases A/B/C (R5-proven structure, 142.9 us build) ----
  float ob = out_b[0];
  for(int pi=w; pi<25; pi+=8){
    int p = p0 + pi;
    // Phase A (lane = q): softmax state
    float sip = sl_i[p];
    float L = -3.0e38f;
    if(lane<N_) L = leaky(sip + sl_j[lane]);
    float M = wmax(L);
    float e = (lane<N_) ? expf(L-M) : 0.f;
    float Dden = wsum(e);
    el[w*64+lane] = e;
    // Phase B (lane = d): S_d
    float S = 0.f;
    const float* hTd = &hT[lane*53];
    const float* elw = &el[w*64];
#pragma unroll 10
    for(int q=0;q<N_;q++) S = fmaf(elw[q], hTd[q], S);
    wc[w*64+lane] = make_float2(S, emb[p*64+lane]*hil[lane]);
    // Phase C (lane = sm): serial 64-d head
    float er = 0.f; int r = 0;
    if(lane>=1 && lane<N_){ int s=lane-1; r = s + (s>=p?1:0); er = el[w*64+r]; }
    float beta  = 1.f/(Dden - er);
    float alpha = er*beta;
    float a_ = ob;
    const float2* wcw = &wc[w*64];
#pragma unroll 8
    for(int d=0;d<64;d++){
      float4 hc = hcl[d];              // LDS same-address broadcast
      float2 se = wcw[d];
      float hrd = hT[d*53 + r];        // lane-varying, <=2-way
      float o  = fmaf(-alpha, hrd, se.x*beta);
      float g  = fmaxf(fmaf(hc.x, o, hc.y), 0.f);
      float xn = fmaxf(fmaf(g, se.y, hc.z), 0.f);
      a_ = fmaf(xn, hc.w, a_);
    }
    if(lane<N_){
      float resid = labels[b*N_+p] - a_;
      atomicAdd(&acc[p*N_+lane].x, resid);
      atomicAdd(&acc[p*N_+lane].y, resid*resid);
    }
  }
}

// K4a: inline F-test -> keep bits; masked attention -> out_raw; So,So^2 atomics.
// (R5-proven verbatim)
__global__ __launch_bounds__(512) void k4a_out(
    const float* __restrict__ h, const float* __restrict__ s_i,
    const float* __restrict__ s_j, const float2* __restrict__ acc,
    const float* __restrict__ gat_bias,
    float* __restrict__ out_raw, float* __restrict__ stats1){
  __shared__ float hT[64*53];
  __shared__ float al[8*64];
  __shared__ int   keepL[8*64];
  __shared__ float2 red[8][64];
  int b = blockIdx.y, tid = threadIdx.x;
  const float* hb = h + (size_t)b*N_*D_;
  for(int i=tid;i<N_*D_;i+=512) hT[(i&63)*53 + (i>>6)] = hb[i];
  __syncthreads();
  int w = tid>>6, lane = tid&63;
  int p = blockIdx.x*8 + w;
  bool act = (p < N_);
  float o = 0.f;
  if(act){
    int kb = 1;
    if(lane < N_-1){
      float2 A2 = acc[p*N_ + lane + 1];
      float2 B2 = acc[p*N_];
      float ma = A2.x*(1.f/B_), mb = B2.x*(1.f/B_);
      float ssw = (A2.y - (float)B_*ma*ma) + (B2.y - (float)B_*mb*mb);
      float dmb = ma - mb;
      float f = (64.f*dmb*dmb) / (ssw*(1.f/254.f));
      kb = (f < FCRIT) ? 0 : 1;        // NaN -> keep (matches reference)
    }
    keepL[w*64+lane] = kb;             // same-wave write/read
    float sip = s_i[b*N_+p];
    float L = -3.0e38f; bool allowed = false;
    if(lane < N_){
      float Lr = leaky(sip + s_j[b*N_+lane]);
      if(lane == p) allowed = true;
      else { int idx = (lane < p) ? lane : lane-1; allowed = keepL[w*64+idx] != 0; }
      L = allowed ? Lr : -1.0e9f;
    }
    float M = wmax(L);
    float e = allowed ? expf(L - M) : 0.f;
    float Dn = wsum(e);
    al[w*64+lane] = e;
    float invD = 1.f/Dn;
    float s = 0.f;
    const float* hTd = &hT[lane*53];
    const float* alw = &al[w*64];
#pragma unroll 10
    for(int q=0;q<N_;q++) s = fmaf(alw[q], hTd[q], s);
    o = fmaf(s, invD, gat_bias[lane]);
    out_raw[((size_t)b*N_+p)*D_ + lane] = o;
  }
  red[w][lane] = act ? make_float2(o, o*o) : make_float2(0.f, 0.f);
  __syncthreads();
  if(w==0){
    float a1=0.f, a2=0.f;
#pragma unroll
    for(int k=0;k<8;k++){ float2 v = red[k][lane]; a1+=v.x; a2+=v.y; }
    int slot = b & 7;
    atomicAdd(&stats1[slot*128 + lane],      a1);
    atomicAdd(&stats1[slot*128 + 64 + lane], a2);
  }
}

// K4b: x3-stats pass (needs global mu1/var1 from stats1) -> stats2 slots
__global__ __launch_bounds__(256) void k4b_stats(
    const float* __restrict__ out_raw, const float* __restrict__ emb,
    const float* __restrict__ bn1_g, const float* __restrict__ bn1_b,
    const float* __restrict__ stats1, float* __restrict__ stats2){
  __shared__ float2 red[4][64];
  int tid = threadIdx.x, w = tid>>6, lane = tid&63;
  float t1=0.f, t2=0.f;
#pragma unroll
  for(int k=0;k<8;k++){ t1 += stats1[k*128+lane]; t2 += stats1[k*128+64+lane]; }
  float mu1  = t1*(1.f/BN);
  float var1 = t2*(1.f/BN) - mu1*mu1;
  float A = bn1_g[lane]/sqrtf(var1+EPSF);
  float C = bn1_b[lane] - mu1*A;
  int r0 = blockIdx.x*64;
  float s1=0.f, s2=0.f;
  for(int i=w;i<64;i+=4){
    int r = r0+i;
    float o = out_raw[(size_t)r*D_ + lane];
    float g = fmaxf(fmaf(A,o,C), 0.f);
    float x3 = g*emb[(r%N_)*D_ + lane];
    s1 += x3; s2 = fmaf(x3,x3,s2);
  }
  red[w][lane] = make_float2(s1,s2);
  __syncthreads();
  if(w==0){
    float2 a=red[0][lane], b=red[1][lane], c=red[2][lane], d=red[3][lane];
    int slot = blockIdx.x & 7;
    atomicAdd(&stats2[slot*128 + lane],      a.x+b.x+c.x+d.x);
    atomicAdd(&stats2[slot*128 + 64 + lane], a.y+b.y+c.y+d.y);
  }
}

// K4c: final head -> d_out[b*N+p]; 16 rows/block
__global__ __launch_bounds__(256) void k4c_final(
    const float* __restrict__ out_raw, const float* __restrict__ emb,
    const float* __restrict__ bn1_g, const float* __restrict__ bn1_b,
    const float* __restrict__ bn2_g, const float* __restrict__ bn2_b,
    const float* __restrict__ out_w, const float* __restrict__ out_b,
    const float* __restrict__ stats1, const float* __restrict__ stats2,
    float* __restrict__ outp){
  int tid = threadIdx.x, w = tid>>6, lane = tid&63;
  float t1=0.f, t2=0.f, t3=0.f, t4=0.f;
#pragma unroll
  for(int k=0;k<8;k++){
    t1 += stats1[k*128+lane]; t2 += stats1[k*128+64+lane];
    t3 += stats2[k*128+lane]; t4 += stats2[k*128+64+lane];
  }
  float mu1  = t1*(1.f/BN), var1 = t2*(1.f/BN) - mu1*mu1;
  float mu2  = t3*(1.f/BN), var2 = t4*(1.f/BN) - mu2*mu2;
  float A1 = bn1_g[lane]/sqrtf(var1+EPSF);
  float C1 = bn1_b[lane] - mu1*A1;
  float A2 = bn2_g[lane]/sqrtf(var2+EPSF);
  float C2 = bn2_b[lane] - mu2*A2;
  float ow = out_w[lane], ob = out_b[0];
#pragma unroll
  for(int j=0;j<4;j++){
    int r = blockIdx.x*16 + w*4 + j;
    float o = out_raw[(size_t)r*D_ + lane];
    float g = fmaxf(fmaf(A1,o,C1), 0.f);
    float x3 = g*emb[(r%N_)*D_ + lane];
    float xn = fmaxf(fmaf(A2,x3,C2), 0.f);
    float pr = wsum(xn*ow);
    if(lane==0) outp[r] = pr + ob;
  }
}

extern "C" void kernel_launch(void* const* d_in, const int* in_sizes, int n_in,
                              void* d_out, int out_size, void* d_ws, size_t ws_size,
                              hipStream_t stream){
  (void)in_sizes; (void)n_in; (void)out_size; (void)ws_size;
  const float* data     = (const float*)d_in[0];
  const float* labels   = (const float*)d_in[1];
  // d_in[2..6]: graph indices / masks — deterministic, not read.
  const float* emb      = (const float*)d_in[7];
  const float* W_lin    = (const float*)d_in[8];
  const float* att_i    = (const float*)d_in[9];
  const float* att_j    = (const float*)d_in[10];
  const float* att_em_i = (const float*)d_in[11];
  const float* att_em_j = (const float*)d_in[12];
  const float* gat_bias = (const float*)d_in[13];
  const float* bn1_g    = (const float*)d_in[14];
  const float* bn1_b    = (const float*)d_in[15];
  const float* bn1_rm   = (const float*)d_in[16];
  const float* bn1_rv   = (const float*)d_in[17];
  const float* bn2_g    = (const float*)d_in[18];
  const float* bn2_b    = (const float*)d_in[19];
  const float* bn2_rm   = (const float*)d_in[20];
  const float* bn2_rv   = (const float*)d_in[21];
  const float* out_w    = (const float*)d_in[22];
  const float* out_b    = (const float*)d_in[23];

  float*  ws      = (float*)d_ws;
  float*  h       = ws;                      // 409600
  float*  s_i     = ws + 409600;             // 6400
  float*  s_j     = ws + 416000;             // 6400
  float*  out_raw = ws + 422400;             // 409600 -> 832000
  float2* acc     = (float2*)(ws + 832000);  // 2500 float2 -> 837000
  float*  stats1  = ws + 837000;             // 1024 -> 838024
  float*  stats2  = ws + 838024;             // 1024 -> 839048
  float*  outp    = (float*)d_out;

  // zero acc + stats1 + stats2 (contiguous 28192 B) — graph-capturable
  hipMemsetAsync((void*)(ws + 832000), 0, (839048 - 832000)*sizeof(float), stream);

  hipLaunchKernelGGL(k2m, dim3(2, B_), dim3(512), 0, stream,
                     data, labels, emb, W_lin, att_i, att_j, att_em_i, att_em_j,
                     bn1_g, bn1_b, bn1_rm, bn1_rv, bn2_g, bn2_b, bn2_rm, bn2_rv,
                     gat_bias, out_w, out_b, h, s_i, s_j, acc);
  hipLaunchKernelGGL(k4a_out, dim3(7, B_), dim3(512), 0, stream,
                     h, s_i, s_j, acc, gat_bias, out_raw, stats1);
  hipLaunchKernelGGL(k4b_stats, dim3(BN/64), dim3(256), 0, stream,
                     out_raw, emb, bn1_g, bn1_b, stats1, stats2);
  hipLaunchKernelGGL(k4c_final, dim3(BN/16), dim3(256), 0, stream,
                     out_raw, emb, bn1_g, bn1_b, bn2_g, bn2_b, out_w, out_b,
                     stats1, stats2, outp);
}